// Round 9
// baseline (545.313 us; speedup 1.0000x reference)
//
#include <hip/hip_runtime.h>
#include <hip/hip_bf16.h>

// GCN layer: out = segment_sum(edge_val * (x@W)[col], row) + bias
// N=100000 nodes, E=640000 edges, D=128.
// Single persistent kernel, 768 blocks (3/CU guaranteed), phases separated by
// device-scope atomic grid barriers:
//   P1 gemm (MFMA, ticket over 6250 tiles) -> P2 edge partition (157 blocks)
//   -> P3 fused LDS-ELL build + branch-free spmm (ticket over 782 slices,
//      inline overflow). Ctrl ints zeroed by one hipMemsetAsync per call.

#define N_NODES 100000
#define N_EDGES 640000
#define D 128
#define ELL_K 16
#define NB 391          // 256-row buckets for partition
#define BCAP 2048       // per-bucket capacity (mean 1638, +10 sigma)
#define CHUNK 4096
#define NCHUNKS 157
#define N_TILES 6250
#define ELL_P 18        // LDS ELL row stride (float2); 144B -> 16B aligned
#define NSLICE 782      // 128-row slices (2 per bucket)
#define GRID 768        // == 3 blocks/CU * 256 CU; co-residency guaranteed
#define OVS 64          // per-slice inline overflow stash

typedef __attribute__((ext_vector_type(8))) short short8;
typedef __attribute__((ext_vector_type(4))) float f32x4;
typedef __attribute__((ext_vector_type(4))) ushort us4;

__device__ __forceinline__ ushort f2bf(float f) {
    uint u = __float_as_uint(f);
    u += 0x7fff + ((u >> 16) & 1);   // RNE
    return (ushort)(u >> 16);
}
__device__ __forceinline__ float bflo(uint u) { return __uint_as_float(u << 16); }
__device__ __forceinline__ float bfhi(uint u) { return __uint_as_float(u & 0xffff0000u); }

__device__ __forceinline__ void gridbar(int* ctr) {
    __syncthreads();
    if (threadIdx.x == 0) {
        __threadfence();
        __hip_atomic_fetch_add(ctr, 1, __ATOMIC_RELEASE, __HIP_MEMORY_SCOPE_AGENT);
        while (__hip_atomic_load(ctr, __ATOMIC_ACQUIRE, __HIP_MEMORY_SCOPE_AGENT) < GRID)
            __builtin_amdgcn_s_sleep(2);
    }
    __syncthreads();
}

// ctrl layout (ints): [0]=barA [1]=barB [2]=tick1 [3]=tick3 [4..394]=bucketCnt
__global__ __launch_bounds__(256, 3) void gcn_fused(const float* __restrict__ x,
                                                    const float* __restrict__ w,
                                                    const float* __restrict__ bias,
                                                    const float* __restrict__ ev,
                                                    const int* __restrict__ row,
                                                    const int* __restrict__ col,
                                                    ushort* __restrict__ y,
                                                    uint2* __restrict__ es0,
                                                    int* __restrict__ ctrl,
                                                    float* __restrict__ out) {
    __shared__ union {
        ushort wt[128 * 128];                         // 32 KB (gemm)
        struct { int hist[NB]; int cur[NB]; } part;   // 3.1 KB (partition)
        struct {
            float2 ell[128 * ELL_P];                  // 18.4 KB
            int lcnt[128];
            float ovVal[OVS]; int ovCol[OVS]; int ovRl[OVS]; int ovCnt;
        } p3;                                         // ~20 KB (ell+spmm)
    } sm;
    __shared__ int sSlice;

    const int tid = threadIdx.x;
    int* barA = ctrl + 0;
    int* barB = ctrl + 1;
    int* tick1 = ctrl + 2;
    int* tick3 = ctrl + 3;
    int* bucketCnt = ctrl + 4;

    // ================= Phase 1: gemm y = bf16(x @ W) =================
    #pragma unroll
    for (int it = 0; it < 16; ++it) {
        int idx4 = tid + it * 256;        // 4096 float4 = 128x128
        int k = idx4 >> 5;
        int n0 = (idx4 & 31) * 4;
        float4 v = *(const float4*)(w + (size_t)idx4 * 4);
        float vv[4] = {v.x, v.y, v.z, v.w};
        #pragma unroll
        for (int q = 0; q < 4; ++q) {
            int n = n0 + q;
            sm.wt[n * 128 + (k ^ ((n & 7) << 3))] = f2bf(vv[q]);
        }
    }
    __syncthreads();

    {
        const int lane = tid & 63;
        const int l15 = lane & 15;
        const int h = lane >> 4;
        while (true) {
            int t;
            if (lane == 0) t = atomicAdd(tick1, 1);
            t = __shfl(t, 0);
            if (t >= N_TILES) break;
            asm volatile("" ::: "memory");
            const float* xr = x + (size_t)(t * 16 + l15) * D;
            float4 xb[8];
            #pragma unroll
            for (int ks = 0; ks < 4; ++ks) {
                xb[2 * ks]     = *(const float4*)(xr + 32 * ks + 8 * h);
                xb[2 * ks + 1] = *(const float4*)(xr + 32 * ks + 8 * h + 4);
            }
            short8 a[4];
            #pragma unroll
            for (int ks = 0; ks < 4; ++ks) {
                const float* p0 = (const float*)&xb[2 * ks];
                const float* p1 = (const float*)&xb[2 * ks + 1];
                a[ks][0] = f2bf(p0[0]); a[ks][1] = f2bf(p0[1]);
                a[ks][2] = f2bf(p0[2]); a[ks][3] = f2bf(p0[3]);
                a[ks][4] = f2bf(p1[0]); a[ks][5] = f2bf(p1[1]);
                a[ks][6] = f2bf(p1[2]); a[ks][7] = f2bf(p1[3]);
            }
            f32x4 acc[8];
            #pragma unroll
            for (int j = 0; j < 8; ++j) acc[j] = (f32x4){0.f, 0.f, 0.f, 0.f};
            #pragma unroll
            for (int ks = 0; ks < 4; ++ks) {
                const int k0 = 32 * ks + 8 * h;
                #pragma unroll
                for (int j = 0; j < 8; ++j) {
                    int n = 16 * j + l15;
                    short8 b = *(const short8*)&sm.wt[n * 128 + (k0 ^ ((n & 7) << 3))];
                    acc[j] = __builtin_amdgcn_mfma_f32_16x16x32_bf16(b, a[ks], acc[j], 0, 0, 0);
                }
            }
            ushort* yn = y + (size_t)(t * 16 + l15) * D;
            #pragma unroll
            for (int j = 0; j < 8; ++j) {
                us4 o;
                o.x = f2bf(acc[j][0]); o.y = f2bf(acc[j][1]);
                o.z = f2bf(acc[j][2]); o.w = f2bf(acc[j][3]);
                *(us4*)(yn + 16 * j + 4 * h) = o;
            }
        }
    }

    gridbar(barA);

    // ================= Phase 2: partition edges -> 256-row buckets ========
    if (blockIdx.x < NCHUNKS) {
        const int base = blockIdx.x * CHUNK;
        for (int t = tid; t < NB; t += 256) sm.part.hist[t] = 0;
        __syncthreads();
        #pragma unroll
        for (int it = 0; it < CHUNK / 256; ++it) {
            int i = base + it * 256 + tid;
            if (i < N_EDGES) atomicAdd(&sm.part.hist[row[i] >> 8], 1);
        }
        __syncthreads();
        for (int t = tid; t < NB; t += 256) {
            int h = sm.part.hist[t];
            int start = (h > 0) ? atomicAdd(&bucketCnt[t], h) : 0;
            sm.part.cur[t] = t * BCAP + start;
        }
        __syncthreads();
        #pragma unroll
        for (int it = 0; it < CHUNK / 256; ++it) {
            int i = base + it * 256 + tid;
            if (i < N_EDGES) {
                int r = row[i];
                int b = r >> 8;
                int p = atomicAdd(&sm.part.cur[b], 1);
                if (p < (b + 1) * BCAP) {   // drop at ~1e-20 probability
                    uint2 e;
                    e.x = __float_as_uint(ev[i]);
                    e.y = (uint)col[i] | ((uint)(r & 255) << 20);
                    es0[p] = e;
                }
            }
        }
    }

    gridbar(barB);

    // ===== Phase 3: per 128-row slice: LDS ELL build + branch-free spmm ====
    {
        const int c16 = tid & 15;
        const int grp = tid >> 4;   // 0..15
        const float4 b0 = *(const float4*)(bias + c16 * 8);
        const float4 b1 = *(const float4*)(bias + c16 * 8 + 4);
        const ushort* yb = y + c16 * 8;

        while (true) {
            if (tid == 0) sSlice = atomicAdd(tick3, 1);
            __syncthreads();
            const int s = sSlice;
            if (s >= NSLICE) break;
            const int b = s >> 1;
            const int half = s & 1;

            // zero ELL + counters
            #pragma unroll
            for (int it = 0; it < 9; ++it) {
                int t = it * 256 + tid;
                if (t < 128 * ELL_P) sm.p3.ell[t] = (float2){0.f, 0.f};
            }
            if (tid < 128) sm.p3.lcnt[tid] = 0;
            if (tid == 0) sm.p3.ovCnt = 0;
            __syncthreads();

            int cnt = bucketCnt[b];
            if (cnt > BCAP) cnt = BCAP;
            const uint2* src = es0 + (size_t)b * BCAP;
            for (int i = tid; i < cnt; i += 256) {
                uint2 e = src[i];
                int r = e.y >> 20;              // 0..255 in bucket
                if ((r >> 7) == half) {
                    int rl = r & 127;
                    int p = atomicAdd(&sm.p3.lcnt[rl], 1);
                    if (p < ELL_K) {
                        float2 rec;
                        rec.x = __uint_as_float(e.x);
                        rec.y = __uint_as_float(e.y & 0xFFFFFu);
                        sm.p3.ell[rl * ELL_P + p] = rec;
                    } else {
                        int q = atomicAdd(&sm.p3.ovCnt, 1);
                        if (q < OVS) {
                            sm.p3.ovVal[q] = __uint_as_float(e.x);
                            sm.p3.ovCol[q] = (int)(e.y & 0xFFFFFu);
                            sm.p3.ovRl[q] = rl;
                        }
                    }
                }
            }
            __syncthreads();

            // gather: group g -> rows g, g+16, ..., g+112
            #pragma unroll 1
            for (int rep = 0; rep < 8; ++rep) {
                const int rl = grp + rep * 16;
                const int n = s * 128 + rl;
                const float4* er = (const float4*)&sm.p3.ell[rl * ELL_P];
                float4 e0 = er[0], e1 = er[1], e2 = er[2], e3 = er[3];
                float4 e4 = er[4], e5 = er[5], e6 = er[6], e7 = er[7];

                #define YLD(c) (*(const uint4*)(yb + ((size_t)__float_as_int(c) << 7)))
                uint4 u0 = YLD(e0.y), u1 = YLD(e0.w), u2 = YLD(e1.y), u3 = YLD(e1.w);
                uint4 u4 = YLD(e2.y), u5 = YLD(e2.w), u6 = YLD(e3.y), u7 = YLD(e3.w);
                uint4 u8 = YLD(e4.y), u9 = YLD(e4.w), uA = YLD(e5.y), uB = YLD(e5.w);
                uint4 uC = YLD(e6.y), uD = YLD(e6.w), uE = YLD(e7.y), uF = YLD(e7.w);
                #undef YLD

                float a[8] = {0.f, 0.f, 0.f, 0.f, 0.f, 0.f, 0.f, 0.f};
                #define FMA8(v, u) do { \
                    a[0] += (v) * bflo((u).x); a[1] += (v) * bfhi((u).x); \
                    a[2] += (v) * bflo((u).y); a[3] += (v) * bfhi((u).y); \
                    a[4] += (v) * bflo((u).z); a[5] += (v) * bfhi((u).z); \
                    a[6] += (v) * bflo((u).w); a[7] += (v) * bfhi((u).w); } while (0)
                FMA8(e0.x, u0); FMA8(e0.z, u1); FMA8(e1.x, u2); FMA8(e1.z, u3);
                FMA8(e2.x, u4); FMA8(e2.z, u5); FMA8(e3.x, u6); FMA8(e3.z, u7);
                FMA8(e4.x, u8); FMA8(e4.z, u9); FMA8(e5.x, uA); FMA8(e5.z, uB);
                FMA8(e6.x, uC); FMA8(e6.z, uD); FMA8(e7.x, uE); FMA8(e7.z, uF);
                #undef FMA8

                if (n < N_NODES) {
                    float4 o0 = {a[0] + b0.x, a[1] + b0.y, a[2] + b0.z, a[3] + b0.w};
                    float4 o1 = {a[4] + b1.x, a[5] + b1.y, a[6] + b1.z, a[7] + b1.w};
                    float* orow = out + ((size_t)n << 7) + c16 * 8;
                    *(float4*)orow = o0;
                    *(float4*)(orow + 4) = o1;
                }
            }
            __syncthreads();

            // inline overflow (rare): owning block, after its own stores
            int nOv = sm.p3.ovCnt;
            if (nOv > OVS) nOv = OVS;
            for (int q = grp; q < nOv; q += 16) {
                float v = sm.p3.ovVal[q];
                int c = sm.p3.ovCol[q];
                int n = s * 128 + sm.p3.ovRl[q];
                uint4 u = *(const uint4*)(yb + ((size_t)c << 7));
                float* orow = out + ((size_t)n << 7) + c16 * 8;
                atomicAdd(orow + 0, v * bflo(u.x)); atomicAdd(orow + 1, v * bfhi(u.x));
                atomicAdd(orow + 2, v * bflo(u.y)); atomicAdd(orow + 3, v * bfhi(u.y));
                atomicAdd(orow + 4, v * bflo(u.z)); atomicAdd(orow + 5, v * bfhi(u.z));
                atomicAdd(orow + 6, v * bflo(u.w)); atomicAdd(orow + 7, v * bfhi(u.w));
            }
            __syncthreads();
        }
    }
}

// ---------------- launch ----------------
extern "C" void kernel_launch(void* const* d_in, const int* in_sizes, int n_in,
                              void* d_out, int out_size, void* d_ws, size_t ws_size,
                              hipStream_t stream) {
    const float* x = (const float*)d_in[0];
    const float* w = (const float*)d_in[1];
    const float* bias = (const float*)d_in[2];
    const float* ev = (const float*)d_in[3];
    const int* row = (const int*)d_in[4];
    const int* col = (const int*)d_in[5];
    float* out = (float*)d_out;

    size_t off = 0;
    auto carve = [&](size_t bytes) -> void* {
        void* p = (char*)d_ws + off;
        off += (bytes + 255) & ~(size_t)255;
        return p;
    };
    ushort* y = (ushort*)carve((size_t)N_NODES * D * sizeof(ushort));
    uint2* es0 = (uint2*)carve((size_t)NB * BCAP * sizeof(uint2));
    int* ctrl = (int*)carve((4 + NB) * sizeof(int));

    hipMemsetAsync(ctrl, 0, (4 + NB) * sizeof(int), stream);
    gcn_fused<<<GRID, 256, 0, stream>>>(x, w, bias, ev, row, col, y, es0, ctrl, out);
}

// Round 10
// 85.893 us; speedup vs baseline: 6.3487x; 6.3487x over previous
//
#include <hip/hip_runtime.h>
#include <hip/hip_bf16.h>

// GCN layer: out = segment_sum(edge_val * (x@W)[col], row) + bias
// N=100000 nodes, E=640000 edges, D=128.
// y bf16. Pipeline (round-4 structure, best measured): gemm (MFMA, reg-B,
// NEW: software-pipelined x prefetch) -> edge partition (256-row buckets) ->
// LDS-built ELL -> spmm (4 nodes/wave, uint4 gathers) -> overflow fixup.

#define N_NODES 100000
#define N_EDGES 640000
#define D 128
#define ELL_K 16
#define OVF_CAP 8192
#define NB 391          // ceil(N_NODES/256) row buckets
#define BCAP 2048       // per-bucket edge capacity (avg 1638)
#define CHUNK 4096
#define NCHUNKS 157     // ceil(N_EDGES/CHUNK)
#define N_TILES 6250

typedef __attribute__((ext_vector_type(8))) short short8;
typedef __attribute__((ext_vector_type(4))) float f32x4;
typedef __attribute__((ext_vector_type(4))) ushort us4;

__device__ __forceinline__ ushort f2bf(float f) {
    uint u = __float_as_uint(f);
    u += 0x7fff + ((u >> 16) & 1);   // RNE
    return (ushort)(u >> 16);
}
__device__ __forceinline__ float bflo(uint u) { return __uint_as_float(u << 16); }
__device__ __forceinline__ float bfhi(uint u) { return __uint_as_float(u & 0xffff0000u); }

// ---------------- GEMM: y(bf16) = x @ W via MFMA 16x16x32 ----------------
// W^T staged in LDS (XOR-swizzled), whole W held in regs as 8x4 B-fragments.
// Swapped-operand mfma so each lane owns one node-row -> ushort4 stores.
// Software pipeline: next tile's 8 x-float4 loads issue BEFORE this tile's
// MFMA block, so HBM latency hides under 32 MFMA + stores. ~230 VGPR peak,
// fits launch_bounds(256,2) (cap 256). Also zeroes bucketCnt/ovfCnt.
__global__ __launch_bounds__(256, 2) void gemm_xw(const float* __restrict__ x,
                                                  const float* __restrict__ w,
                                                  ushort* __restrict__ y,
                                                  int* __restrict__ bucketCnt) {
    __shared__ ushort wt[128 * 128];  // 32KB; idx = n*128 + (k ^ ((n&7)<<3))
    const int tid = threadIdx.x;

    int gz = blockIdx.x * 256 + tid;
    if (gz <= NB) bucketCnt[gz] = 0;   // [NB] doubles as ovfCnt

    #pragma unroll
    for (int it = 0; it < 16; ++it) {
        int idx4 = tid + it * 256;        // 4096 float4 = 128x128
        int k = idx4 >> 5;
        int n0 = (idx4 & 31) * 4;
        float4 v = *(const float4*)(w + (size_t)idx4 * 4);
        float vv[4] = {v.x, v.y, v.z, v.w};
        #pragma unroll
        for (int q = 0; q < 4; ++q) {
            int n = n0 + q;
            wt[n * 128 + (k ^ ((n & 7) << 3))] = f2bf(vv[q]);
        }
    }
    __syncthreads();

    const int lane = tid & 63;
    const int l15 = lane & 15;
    const int h = lane >> 4;

    short8 bfr[8][4];
    #pragma unroll
    for (int j = 0; j < 8; ++j) {
        int n = 16 * j + l15;
        #pragma unroll
        for (int ks = 0; ks < 4; ++ks) {
            int k0 = 32 * ks + 8 * h;
            bfr[j][ks] = *(const short8*)&wt[n * 128 + (k0 ^ ((n & 7) << 3))];
        }
    }

    const int waveGlobal = blockIdx.x * 4 + (tid >> 6);
    const int nWaves = gridDim.x * 4;   // 2048

    int t = waveGlobal;
    if (t < N_TILES) {
        // prologue: load + convert tile t
        short8 a[4];
        {
            const float* xr = x + (size_t)(t * 16 + l15) * D;
            float4 xb[8];
            #pragma unroll
            for (int ks = 0; ks < 4; ++ks) {
                xb[2 * ks]     = *(const float4*)(xr + 32 * ks + 8 * h);
                xb[2 * ks + 1] = *(const float4*)(xr + 32 * ks + 8 * h + 4);
            }
            #pragma unroll
            for (int ks = 0; ks < 4; ++ks) {
                const float* p0 = (const float*)&xb[2 * ks];
                const float* p1 = (const float*)&xb[2 * ks + 1];
                a[ks][0] = f2bf(p0[0]); a[ks][1] = f2bf(p0[1]);
                a[ks][2] = f2bf(p0[2]); a[ks][3] = f2bf(p0[3]);
                a[ks][4] = f2bf(p1[0]); a[ks][5] = f2bf(p1[1]);
                a[ks][6] = f2bf(p1[2]); a[ks][7] = f2bf(p1[3]);
            }
        }
        #pragma unroll 1
        while (true) {
            const int tn = t + nWaves;
            const bool more = tn < N_TILES;

            // issue next tile's loads early (hidden under MFMA + stores)
            float4 xb2[8];
            if (more) {
                const float* xr = x + (size_t)(tn * 16 + l15) * D;
                #pragma unroll
                for (int ks = 0; ks < 4; ++ks) {
                    xb2[2 * ks]     = *(const float4*)(xr + 32 * ks + 8 * h);
                    xb2[2 * ks + 1] = *(const float4*)(xr + 32 * ks + 8 * h + 4);
                }
            }

            f32x4 acc[8];
            #pragma unroll
            for (int j = 0; j < 8; ++j) acc[j] = (f32x4){0.f, 0.f, 0.f, 0.f};
            #pragma unroll
            for (int ks = 0; ks < 4; ++ks) {
                #pragma unroll
                for (int j = 0; j < 8; ++j)
                    acc[j] = __builtin_amdgcn_mfma_f32_16x16x32_bf16(bfr[j][ks], a[ks], acc[j], 0, 0, 0);
            }
            // node = t*16 + l15, channel = 16j + 4h + r
            ushort* yn = y + (size_t)(t * 16 + l15) * D;
            #pragma unroll
            for (int j = 0; j < 8; ++j) {
                us4 o;
                o.x = f2bf(acc[j][0]); o.y = f2bf(acc[j][1]);
                o.z = f2bf(acc[j][2]); o.w = f2bf(acc[j][3]);
                *(us4*)(yn + 16 * j + 4 * h) = o;
            }

            if (!more) break;
            #pragma unroll
            for (int ks = 0; ks < 4; ++ks) {
                const float* p0 = (const float*)&xb2[2 * ks];
                const float* p1 = (const float*)&xb2[2 * ks + 1];
                a[ks][0] = f2bf(p0[0]); a[ks][1] = f2bf(p0[1]);
                a[ks][2] = f2bf(p0[2]); a[ks][3] = f2bf(p0[3]);
                a[ks][4] = f2bf(p1[0]); a[ks][5] = f2bf(p1[1]);
                a[ks][6] = f2bf(p1[2]); a[ks][7] = f2bf(p1[3]);
            }
            t = tn;
        }
    }
}

// ---------------- partition: edges -> 256-row buckets ----------------
__global__ __launch_bounds__(256) void partition_edges(const float* __restrict__ ev,
                                                       const int* __restrict__ row,
                                                       const int* __restrict__ col,
                                                       int* __restrict__ bucketCnt,
                                                       uint2* __restrict__ es0,
                                                       int* __restrict__ ovfCnt,
                                                       int* __restrict__ ovfRow,
                                                       int* __restrict__ ovfCol,
                                                       float* __restrict__ ovfVal) {
    __shared__ int hist[NB];
    __shared__ int cur[NB];
    const int tid = threadIdx.x;
    const int base = blockIdx.x * CHUNK;

    for (int t = tid; t < NB; t += 256) hist[t] = 0;
    __syncthreads();

    #pragma unroll
    for (int it = 0; it < CHUNK / 256; ++it) {
        int i = base + it * 256 + tid;
        if (i < N_EDGES) atomicAdd(&hist[row[i] >> 8], 1);
    }
    __syncthreads();

    for (int t = tid; t < NB; t += 256) {
        int h = hist[t];
        int start = (h > 0) ? atomicAdd(&bucketCnt[t], h) : 0;
        cur[t] = t * BCAP + start;
    }
    __syncthreads();

    #pragma unroll
    for (int it = 0; it < CHUNK / 256; ++it) {
        int i = base + it * 256 + tid;
        if (i < N_EDGES) {
            int r = row[i];
            int b = r >> 8;
            int p = atomicAdd(&cur[b], 1);
            if (p < (b + 1) * BCAP) {
                uint2 e;
                e.x = __float_as_uint(ev[i]);
                e.y = (uint)col[i] | ((uint)(r & 255) << 20);
                es0[p] = e;
            } else {
                int q = atomicAdd(ovfCnt, 1);
                if (q < OVF_CAP) {
                    ovfRow[q] = r;
                    ovfCol[q] = col[i];
                    ovfVal[q] = ev[i];
                }
            }
        }
    }
}

// ---------------- build ELL in LDS, write coalesced ----------------
__global__ __launch_bounds__(256) void build_ell(const uint2* __restrict__ es0,
                                                 const int* __restrict__ bucketCnt,
                                                 float2* __restrict__ es,
                                                 int* __restrict__ counts,
                                                 int* __restrict__ ovfCnt,
                                                 int* __restrict__ ovfRow,
                                                 int* __restrict__ ovfCol,
                                                 float* __restrict__ ovfVal) {
    __shared__ float2 ell[256 * ELL_K];   // 32KB
    __shared__ int lcnt[256];
    const int tid = threadIdx.x;
    const int b = blockIdx.x;

    lcnt[tid] = 0;
    __syncthreads();

    int cnt = bucketCnt[b];
    if (cnt > BCAP) cnt = BCAP;
    const uint2* src = es0 + (size_t)b * BCAP;

    for (int i = tid; i < cnt; i += 256) {
        uint2 e = src[i];
        int r = e.y >> 20;
        int p = atomicAdd(&lcnt[r], 1);
        if (p < ELL_K) {
            float2 rec;
            rec.x = __uint_as_float(e.x);
            rec.y = __uint_as_float(e.y & 0xFFFFFu);
            ell[r * ELL_K + p] = rec;
        } else {
            int q = atomicAdd(ovfCnt, 1);
            if (q < OVF_CAP) {
                ovfRow[q] = b * 256 + r;
                ovfCol[q] = (int)(e.y & 0xFFFFFu);
                ovfVal[q] = __uint_as_float(e.x);
            }
        }
    }
    __syncthreads();

    const int nbase = b * 256;
    int nvalid = N_NODES - nbase;
    if (nvalid > 256) nvalid = 256;

    if (tid < nvalid) counts[nbase + tid] = lcnt[tid];

    float4* dst4 = (float4*)(es + (size_t)nbase * ELL_K);
    const float4* ell4 = (const float4*)ell;
    for (int t = tid; t < nvalid * (ELL_K / 2); t += 256)
        dst4[t] = ell4[t];
}

// ---------------- SpMM: 4 nodes per wave (16 lanes each), uint4 gathers ----
__global__ __launch_bounds__(256) void spmm_ell(const ushort* __restrict__ y,
                                                const float2* __restrict__ es,
                                                const int* __restrict__ counts,
                                                const float* __restrict__ bias,
                                                float* __restrict__ out) {
    const int tid = threadIdx.x;
    const int lane = tid & 63;
    const int c16 = lane & 15;       // channel group: ch c16*8 .. c16*8+7
    const int sub = lane >> 4;       // node sub-index 0..3
    const int wid = blockIdx.x * 4 + (tid >> 6);

    const float4 b0 = *(const float4*)(bias + c16 * 8);
    const float4 b1 = *(const float4*)(bias + c16 * 8 + 4);

    #pragma unroll 1
    for (int rep = 0; rep < 2; ++rep) {
        const int n = wid * 8 + rep * 4 + sub;
        int deg = counts[n];
        if (deg > ELL_K) deg = ELL_K;
        const float4* er = (const float4*)(es + (size_t)n * ELL_K);  // 8 float4

        float a0 = 0.f, a1 = 0.f, a2 = 0.f, a3 = 0.f;
        float a4 = 0.f, a5 = 0.f, a6 = 0.f, a7 = 0.f;

        #pragma unroll
        for (int g = 0; g < 4; ++g) {
            if (4 * g < deg) {
                float4 sA = er[2 * g];
                float4 sB = er[2 * g + 1];
                int c0 = __float_as_int(sA.y);
                int c1 = (4 * g + 1 < deg) ? __float_as_int(sA.w) : c0;
                int c2 = (4 * g + 2 < deg) ? __float_as_int(sB.y) : c0;
                int c3 = (4 * g + 3 < deg) ? __float_as_int(sB.w) : c0;
                uint4 u0 = *(const uint4*)(y + ((size_t)c0 << 7) + c16 * 8);
                uint4 u1 = *(const uint4*)(y + ((size_t)c1 << 7) + c16 * 8);
                uint4 u2 = *(const uint4*)(y + ((size_t)c2 << 7) + c16 * 8);
                uint4 u3 = *(const uint4*)(y + ((size_t)c3 << 7) + c16 * 8);
                float v0 = sA.x;
                float v1 = (4 * g + 1 < deg) ? sA.z : 0.f;
                float v2 = (4 * g + 2 < deg) ? sB.x : 0.f;
                float v3 = (4 * g + 3 < deg) ? sB.z : 0.f;
                a0 += v0 * bflo(u0.x); a1 += v0 * bfhi(u0.x);
                a2 += v0 * bflo(u0.y); a3 += v0 * bfhi(u0.y);
                a4 += v0 * bflo(u0.z); a5 += v0 * bfhi(u0.z);
                a6 += v0 * bflo(u0.w); a7 += v0 * bfhi(u0.w);
                a0 += v1 * bflo(u1.x); a1 += v1 * bfhi(u1.x);
                a2 += v1 * bflo(u1.y); a3 += v1 * bfhi(u1.y);
                a4 += v1 * bflo(u1.z); a5 += v1 * bfhi(u1.z);
                a6 += v1 * bflo(u1.w); a7 += v1 * bfhi(u1.w);
                a0 += v2 * bflo(u2.x); a1 += v2 * bfhi(u2.x);
                a2 += v2 * bflo(u2.y); a3 += v2 * bfhi(u2.y);
                a4 += v2 * bflo(u2.z); a5 += v2 * bfhi(u2.z);
                a6 += v2 * bflo(u2.w); a7 += v2 * bfhi(u2.w);
                a0 += v3 * bflo(u3.x); a1 += v3 * bfhi(u3.x);
                a2 += v3 * bflo(u3.y); a3 += v3 * bfhi(u3.y);
                a4 += v3 * bflo(u3.z); a5 += v3 * bfhi(u3.z);
                a6 += v3 * bflo(u3.w); a7 += v3 * bfhi(u3.w);
            }
        }
        float4 o0 = {a0 + b0.x, a1 + b0.y, a2 + b0.z, a3 + b0.w};
        float4 o1 = {a4 + b1.x, a5 + b1.y, a6 + b1.z, a7 + b1.w};
        float* orow = out + ((size_t)n << 7) + c16 * 8;
        *(float4*)orow = o0;
        *(float4*)(orow + 4) = o1;
    }
}

// ---------------- overflow fixup (rare) ----------------
__global__ void ovf_fix(const ushort* __restrict__ y, const int* __restrict__ ovfRow,
                        const int* __restrict__ ovfCol, const float* __restrict__ ovfVal,
                        const int* __restrict__ ovfCnt, float* __restrict__ out) {
    int nOvf = *ovfCnt;
    if (nOvf > OVF_CAP) nOvf = OVF_CAP;
    int total = nOvf * 32;
    for (int idx = blockIdx.x * 256 + threadIdx.x; idx < total; idx += gridDim.x * 256) {
        int e = idx >> 5;
        int c = idx & 31;
        int r = ovfRow[e];
        int col = ovfCol[e];
        float v = ovfVal[e];
        uint2 u = *(const uint2*)(y + ((size_t)col << 7) + c * 4);
        atomicAdd(&out[(size_t)r * D + c * 4 + 0], v * bflo(u.x));
        atomicAdd(&out[(size_t)r * D + c * 4 + 1], v * bfhi(u.x));
        atomicAdd(&out[(size_t)r * D + c * 4 + 2], v * bflo(u.y));
        atomicAdd(&out[(size_t)r * D + c * 4 + 3], v * bfhi(u.y));
    }
}

// ---------------- launch ----------------
extern "C" void kernel_launch(void* const* d_in, const int* in_sizes, int n_in,
                              void* d_out, int out_size, void* d_ws, size_t ws_size,
                              hipStream_t stream) {
    const float* x = (const float*)d_in[0];
    const float* w = (const float*)d_in[1];
    const float* bias = (const float*)d_in[2];
    const float* ev = (const float*)d_in[3];
    const int* row = (const int*)d_in[4];
    const int* col = (const int*)d_in[5];
    float* out = (float*)d_out;

    size_t off = 0;
    auto carve = [&](size_t bytes) -> void* {
        void* p = (char*)d_ws + off;
        off += (bytes + 255) & ~(size_t)255;
        return p;
    };
    ushort* y = (ushort*)carve((size_t)N_NODES * D * sizeof(ushort));
    int* counts = (int*)carve((size_t)N_NODES * sizeof(int));
    float2* es = (float2*)carve((size_t)N_NODES * ELL_K * sizeof(float2));
    uint2* es0 = (uint2*)carve((size_t)NB * BCAP * sizeof(uint2));
    int* bucketCnt = (int*)carve((NB + 1) * sizeof(int));  // [NB] = ovfCnt
    int* ovfCnt = bucketCnt + NB;
    int* ovfRow = (int*)carve(OVF_CAP * sizeof(int));
    int* ovfCol = (int*)carve(OVF_CAP * sizeof(int));
    float* ovfVal = (float*)carve(OVF_CAP * sizeof(float));

    gemm_xw<<<512, 256, 0, stream>>>(x, w, y, bucketCnt);
    partition_edges<<<NCHUNKS, 256, 0, stream>>>(ev, row, col, bucketCnt, es0,
                                                 ovfCnt, ovfRow, ovfCol, ovfVal);
    build_ell<<<NB, 256, 0, stream>>>(es0, bucketCnt, es, counts,
                                      ovfCnt, ovfRow, ovfCol, ovfVal);
    spmm_ell<<<N_NODES / 32, 256, 0, stream>>>(y, es, counts, bias, out);
    ovf_fix<<<16, 256, 0, stream>>>(y, ovfRow, ovfCol, ovfVal, ovfCnt, out);
}

// Round 12
// 85.449 us; speedup vs baseline: 6.3817x; 1.0052x over previous
//
#include <hip/hip_runtime.h>
#include <hip/hip_bf16.h>

// GCN layer: out = segment_sum(edge_val * (x@W)[col], row) + bias
// N=100000 nodes, E=640000 edges, D=128.
// y bf16. Pipeline (round-4 structure): gemm (MFMA, reg-B, x prefetch,
// f32->bf16 via __float2bfloat16 so the compiler emits native cvt) ->
// edge partition -> LDS-built ELL -> spmm (4 nodes/wave, uint4 gathers) ->
// overflow fixup.

#define N_NODES 100000
#define N_EDGES 640000
#define D 128
#define ELL_K 16
#define OVF_CAP 8192
#define NB 391          // ceil(N_NODES/256) row buckets
#define BCAP 2048       // per-bucket edge capacity (avg 1638)
#define CHUNK 4096
#define NCHUNKS 157     // ceil(N_EDGES/CHUNK)
#define N_TILES 6250

typedef __attribute__((ext_vector_type(8))) short short8;
typedef __attribute__((ext_vector_type(4))) float f32x4;
typedef __attribute__((ext_vector_type(4))) ushort us4;

// f32 -> bf16 (RNE) through the compiler's native path: on gfx950 LLVM
// pattern-matches pairs of these into v_cvt_pk_bf16_f32. (Hand-written
// inline asm for cvt_pk produced NaN in round 11 -- do not hand-write.)
__device__ __forceinline__ ushort f2bf(float f) {
    __hip_bfloat16 h = __float2bfloat16(f);
    return __builtin_bit_cast(ushort, h);
}
__device__ __forceinline__ float bflo(uint u) { return __uint_as_float(u << 16); }
__device__ __forceinline__ float bfhi(uint u) { return __uint_as_float(u & 0xffff0000u); }

// ---------------- GEMM: y(bf16) = x @ W via MFMA 16x16x32 ----------------
// W^T staged in LDS (XOR-swizzled), whole W held in regs as 8x4 B-fragments.
// Swapped-operand mfma so each lane owns one node-row -> ushort4 stores.
// Next tile's 8 x-float4 loads issue before the MFMA block (latency hiding).
// Also zeroes bucketCnt/ovfCnt.
__global__ __launch_bounds__(256, 2) void gemm_xw(const float* __restrict__ x,
                                                  const float* __restrict__ w,
                                                  ushort* __restrict__ y,
                                                  int* __restrict__ bucketCnt) {
    __shared__ ushort wt[128 * 128];  // 32KB; idx = n*128 + (k ^ ((n&7)<<3))
    const int tid = threadIdx.x;

    int gz = blockIdx.x * 256 + tid;
    if (gz <= NB) bucketCnt[gz] = 0;   // [NB] doubles as ovfCnt

    #pragma unroll
    for (int it = 0; it < 16; ++it) {
        int idx4 = tid + it * 256;        // 4096 float4 = 128x128
        int k = idx4 >> 5;
        int n0 = (idx4 & 31) * 4;
        float4 v = *(const float4*)(w + (size_t)idx4 * 4);
        float vv[4] = {v.x, v.y, v.z, v.w};
        #pragma unroll
        for (int q = 0; q < 4; ++q) {
            int n = n0 + q;
            wt[n * 128 + (k ^ ((n & 7) << 3))] = f2bf(vv[q]);
        }
    }
    __syncthreads();

    const int lane = tid & 63;
    const int l15 = lane & 15;
    const int h = lane >> 4;

    short8 bfr[8][4];
    #pragma unroll
    for (int j = 0; j < 8; ++j) {
        int n = 16 * j + l15;
        #pragma unroll
        for (int ks = 0; ks < 4; ++ks) {
            int k0 = 32 * ks + 8 * h;
            bfr[j][ks] = *(const short8*)&wt[n * 128 + (k0 ^ ((n & 7) << 3))];
        }
    }

    const int waveGlobal = blockIdx.x * 4 + (tid >> 6);
    const int nWaves = gridDim.x * 4;   // 2048

    int t = waveGlobal;
    if (t < N_TILES) {
        // prologue: load + convert tile t
        short8 a[4];
        {
            const float* xr = x + (size_t)(t * 16 + l15) * D;
            float4 xb[8];
            #pragma unroll
            for (int ks = 0; ks < 4; ++ks) {
                xb[2 * ks]     = *(const float4*)(xr + 32 * ks + 8 * h);
                xb[2 * ks + 1] = *(const float4*)(xr + 32 * ks + 8 * h + 4);
            }
            #pragma unroll
            for (int ks = 0; ks < 4; ++ks) {
                const float* p0 = (const float*)&xb[2 * ks];
                const float* p1 = (const float*)&xb[2 * ks + 1];
                a[ks][0] = f2bf(p0[0]); a[ks][1] = f2bf(p0[1]);
                a[ks][2] = f2bf(p0[2]); a[ks][3] = f2bf(p0[3]);
                a[ks][4] = f2bf(p1[0]); a[ks][5] = f2bf(p1[1]);
                a[ks][6] = f2bf(p1[2]); a[ks][7] = f2bf(p1[3]);
            }
        }
        #pragma unroll 1
        while (true) {
            const int tn = t + nWaves;
            const bool more = tn < N_TILES;

            // issue next tile's loads early (hidden under MFMA + stores)
            float4 xb2[8];
            if (more) {
                const float* xr = x + (size_t)(tn * 16 + l15) * D;
                #pragma unroll
                for (int ks = 0; ks < 4; ++ks) {
                    xb2[2 * ks]     = *(const float4*)(xr + 32 * ks + 8 * h);
                    xb2[2 * ks + 1] = *(const float4*)(xr + 32 * ks + 8 * h + 4);
                }
            }

            f32x4 acc[8];
            #pragma unroll
            for (int j = 0; j < 8; ++j) acc[j] = (f32x4){0.f, 0.f, 0.f, 0.f};
            #pragma unroll
            for (int ks = 0; ks < 4; ++ks) {
                #pragma unroll
                for (int j = 0; j < 8; ++j)
                    acc[j] = __builtin_amdgcn_mfma_f32_16x16x32_bf16(bfr[j][ks], a[ks], acc[j], 0, 0, 0);
            }
            // node = t*16 + l15, channel = 16j + 4h + r
            ushort* yn = y + (size_t)(t * 16 + l15) * D;
            #pragma unroll
            for (int j = 0; j < 8; ++j) {
                us4 o;
                o.x = f2bf(acc[j][0]); o.y = f2bf(acc[j][1]);
                o.z = f2bf(acc[j][2]); o.w = f2bf(acc[j][3]);
                *(us4*)(yn + 16 * j + 4 * h) = o;
            }

            if (!more) break;
            #pragma unroll
            for (int ks = 0; ks < 4; ++ks) {
                const float* p0 = (const float*)&xb2[2 * ks];
                const float* p1 = (const float*)&xb2[2 * ks + 1];
                a[ks][0] = f2bf(p0[0]); a[ks][1] = f2bf(p0[1]);
                a[ks][2] = f2bf(p0[2]); a[ks][3] = f2bf(p0[3]);
                a[ks][4] = f2bf(p1[0]); a[ks][5] = f2bf(p1[1]);
                a[ks][6] = f2bf(p1[2]); a[ks][7] = f2bf(p1[3]);
            }
            t = tn;
        }
    }
}

// ---------------- partition: edges -> 256-row buckets ----------------
__global__ __launch_bounds__(256) void partition_edges(const float* __restrict__ ev,
                                                       const int* __restrict__ row,
                                                       const int* __restrict__ col,
                                                       int* __restrict__ bucketCnt,
                                                       uint2* __restrict__ es0,
                                                       int* __restrict__ ovfCnt,
                                                       int* __restrict__ ovfRow,
                                                       int* __restrict__ ovfCol,
                                                       float* __restrict__ ovfVal) {
    __shared__ int hist[NB];
    __shared__ int cur[NB];
    const int tid = threadIdx.x;
    const int base = blockIdx.x * CHUNK;

    for (int t = tid; t < NB; t += 256) hist[t] = 0;
    __syncthreads();

    #pragma unroll
    for (int it = 0; it < CHUNK / 256; ++it) {
        int i = base + it * 256 + tid;
        if (i < N_EDGES) atomicAdd(&hist[row[i] >> 8], 1);
    }
    __syncthreads();

    for (int t = tid; t < NB; t += 256) {
        int h = hist[t];
        int start = (h > 0) ? atomicAdd(&bucketCnt[t], h) : 0;
        cur[t] = t * BCAP + start;
    }
    __syncthreads();

    #pragma unroll
    for (int it = 0; it < CHUNK / 256; ++it) {
        int i = base + it * 256 + tid;
        if (i < N_EDGES) {
            int r = row[i];
            int b = r >> 8;
            int p = atomicAdd(&cur[b], 1);
            if (p < (b + 1) * BCAP) {
                uint2 e;
                e.x = __float_as_uint(ev[i]);
                e.y = (uint)col[i] | ((uint)(r & 255) << 20);
                es0[p] = e;
            } else {
                int q = atomicAdd(ovfCnt, 1);
                if (q < OVF_CAP) {
                    ovfRow[q] = r;
                    ovfCol[q] = col[i];
                    ovfVal[q] = ev[i];
                }
            }
        }
    }
}

// ---------------- build ELL in LDS, write coalesced ----------------
__global__ __launch_bounds__(256) void build_ell(const uint2* __restrict__ es0,
                                                 const int* __restrict__ bucketCnt,
                                                 float2* __restrict__ es,
                                                 int* __restrict__ counts,
                                                 int* __restrict__ ovfCnt,
                                                 int* __restrict__ ovfRow,
                                                 int* __restrict__ ovfCol,
                                                 float* __restrict__ ovfVal) {
    __shared__ float2 ell[256 * ELL_K];   // 32KB
    __shared__ int lcnt[256];
    const int tid = threadIdx.x;
    const int b = blockIdx.x;

    lcnt[tid] = 0;
    __syncthreads();

    int cnt = bucketCnt[b];
    if (cnt > BCAP) cnt = BCAP;
    const uint2* src = es0 + (size_t)b * BCAP;

    for (int i = tid; i < cnt; i += 256) {
        uint2 e = src[i];
        int r = e.y >> 20;
        int p = atomicAdd(&lcnt[r], 1);
        if (p < ELL_K) {
            float2 rec;
            rec.x = __uint_as_float(e.x);
            rec.y = __uint_as_float(e.y & 0xFFFFFu);
            ell[r * ELL_K + p] = rec;
        } else {
            int q = atomicAdd(ovfCnt, 1);
            if (q < OVF_CAP) {
                ovfRow[q] = b * 256 + r;
                ovfCol[q] = (int)(e.y & 0xFFFFFu);
                ovfVal[q] = __uint_as_float(e.x);
            }
        }
    }
    __syncthreads();

    const int nbase = b * 256;
    int nvalid = N_NODES - nbase;
    if (nvalid > 256) nvalid = 256;

    if (tid < nvalid) counts[nbase + tid] = lcnt[tid];

    float4* dst4 = (float4*)(es + (size_t)nbase * ELL_K);
    const float4* ell4 = (const float4*)ell;
    for (int t = tid; t < nvalid * (ELL_K / 2); t += 256)
        dst4[t] = ell4[t];
}

// ---------------- SpMM: 4 nodes per wave (16 lanes each), uint4 gathers ----
__global__ __launch_bounds__(256) void spmm_ell(const ushort* __restrict__ y,
                                                const float2* __restrict__ es,
                                                const int* __restrict__ counts,
                                                const float* __restrict__ bias,
                                                float* __restrict__ out) {
    const int tid = threadIdx.x;
    const int lane = tid & 63;
    const int c16 = lane & 15;       // channel group: ch c16*8 .. c16*8+7
    const int sub = lane >> 4;       // node sub-index 0..3
    const int wid = blockIdx.x * 4 + (tid >> 6);

    const float4 b0 = *(const float4*)(bias + c16 * 8);
    const float4 b1 = *(const float4*)(bias + c16 * 8 + 4);

    #pragma unroll 1
    for (int rep = 0; rep < 2; ++rep) {
        const int n = wid * 8 + rep * 4 + sub;
        int deg = counts[n];
        if (deg > ELL_K) deg = ELL_K;
        const float4* er = (const float4*)(es + (size_t)n * ELL_K);  // 8 float4

        float a0 = 0.f, a1 = 0.f, a2 = 0.f, a3 = 0.f;
        float a4 = 0.f, a5 = 0.f, a6 = 0.f, a7 = 0.f;

        #pragma unroll
        for (int g = 0; g < 4; ++g) {
            if (4 * g < deg) {
                float4 sA = er[2 * g];
                float4 sB = er[2 * g + 1];
                int c0 = __float_as_int(sA.y);
                int c1 = (4 * g + 1 < deg) ? __float_as_int(sA.w) : c0;
                int c2 = (4 * g + 2 < deg) ? __float_as_int(sB.y) : c0;
                int c3 = (4 * g + 3 < deg) ? __float_as_int(sB.w) : c0;
                uint4 u0 = *(const uint4*)(y + ((size_t)c0 << 7) + c16 * 8);
                uint4 u1 = *(const uint4*)(y + ((size_t)c1 << 7) + c16 * 8);
                uint4 u2 = *(const uint4*)(y + ((size_t)c2 << 7) + c16 * 8);
                uint4 u3 = *(const uint4*)(y + ((size_t)c3 << 7) + c16 * 8);
                float v0 = sA.x;
                float v1 = (4 * g + 1 < deg) ? sA.z : 0.f;
                float v2 = (4 * g + 2 < deg) ? sB.x : 0.f;
                float v3 = (4 * g + 3 < deg) ? sB.z : 0.f;
                a0 += v0 * bflo(u0.x); a1 += v0 * bfhi(u0.x);
                a2 += v0 * bflo(u0.y); a3 += v0 * bfhi(u0.y);
                a4 += v0 * bflo(u0.z); a5 += v0 * bfhi(u0.z);
                a6 += v0 * bflo(u0.w); a7 += v0 * bfhi(u0.w);
                a0 += v1 * bflo(u1.x); a1 += v1 * bfhi(u1.x);
                a2 += v1 * bflo(u1.y); a3 += v1 * bfhi(u1.y);
                a4 += v1 * bflo(u1.z); a5 += v1 * bfhi(u1.z);
                a6 += v1 * bflo(u1.w); a7 += v1 * bfhi(u1.w);
                a0 += v2 * bflo(u2.x); a1 += v2 * bfhi(u2.x);
                a2 += v2 * bflo(u2.y); a3 += v2 * bfhi(u2.y);
                a4 += v2 * bflo(u2.z); a5 += v2 * bfhi(u2.z);
                a6 += v2 * bflo(u2.w); a7 += v2 * bfhi(u2.w);
                a0 += v3 * bflo(u3.x); a1 += v3 * bfhi(u3.x);
                a2 += v3 * bflo(u3.y); a3 += v3 * bfhi(u3.y);
                a4 += v3 * bflo(u3.z); a5 += v3 * bfhi(u3.z);
                a6 += v3 * bflo(u3.w); a7 += v3 * bfhi(u3.w);
            }
        }
        float4 o0 = {a0 + b0.x, a1 + b0.y, a2 + b0.z, a3 + b0.w};
        float4 o1 = {a4 + b1.x, a5 + b1.y, a6 + b1.z, a7 + b1.w};
        float* orow = out + ((size_t)n << 7) + c16 * 8;
        *(float4*)orow = o0;
        *(float4*)(orow + 4) = o1;
    }
}

// ---------------- overflow fixup (rare) ----------------
__global__ void ovf_fix(const ushort* __restrict__ y, const int* __restrict__ ovfRow,
                        const int* __restrict__ ovfCol, const float* __restrict__ ovfVal,
                        const int* __restrict__ ovfCnt, float* __restrict__ out) {
    int nOvf = *ovfCnt;
    if (nOvf > OVF_CAP) nOvf = OVF_CAP;
    int total = nOvf * 32;
    for (int idx = blockIdx.x * 256 + threadIdx.x; idx < total; idx += gridDim.x * 256) {
        int e = idx >> 5;
        int c = idx & 31;
        int r = ovfRow[e];
        int col = ovfCol[e];
        float v = ovfVal[e];
        uint2 u = *(const uint2*)(y + ((size_t)col << 7) + c * 4);
        atomicAdd(&out[(size_t)r * D + c * 4 + 0], v * bflo(u.x));
        atomicAdd(&out[(size_t)r * D + c * 4 + 1], v * bfhi(u.x));
        atomicAdd(&out[(size_t)r * D + c * 4 + 2], v * bflo(u.y));
        atomicAdd(&out[(size_t)r * D + c * 4 + 3], v * bfhi(u.y));
    }
}

// ---------------- launch ----------------
extern "C" void kernel_launch(void* const* d_in, const int* in_sizes, int n_in,
                              void* d_out, int out_size, void* d_ws, size_t ws_size,
                              hipStream_t stream) {
    const float* x = (const float*)d_in[0];
    const float* w = (const float*)d_in[1];
    const float* bias = (const float*)d_in[2];
    const float* ev = (const float*)d_in[3];
    const int* row = (const int*)d_in[4];
    const int* col = (const int*)d_in[5];
    float* out = (float*)d_out;

    size_t off = 0;
    auto carve = [&](size_t bytes) -> void* {
        void* p = (char*)d_ws + off;
        off += (bytes + 255) & ~(size_t)255;
        return p;
    };
    ushort* y = (ushort*)carve((size_t)N_NODES * D * sizeof(ushort));
    int* counts = (int*)carve((size_t)N_NODES * sizeof(int));
    float2* es = (float2*)carve((size_t)N_NODES * ELL_K * sizeof(float2));
    uint2* es0 = (uint2*)carve((size_t)NB * BCAP * sizeof(uint2));
    int* bucketCnt = (int*)carve((NB + 1) * sizeof(int));  // [NB] = ovfCnt
    int* ovfCnt = bucketCnt + NB;
    int* ovfRow = (int*)carve(OVF_CAP * sizeof(int));
    int* ovfCol = (int*)carve(OVF_CAP * sizeof(int));
    float* ovfVal = (float*)carve(OVF_CAP * sizeof(float));

    gemm_xw<<<512, 256, 0, stream>>>(x, w, y, bucketCnt);
    partition_edges<<<NCHUNKS, 256, 0, stream>>>(ev, row, col, bucketCnt, es0,
                                                 ovfCnt, ovfRow, ovfCol, ovfVal);
    build_ell<<<NB, 256, 0, stream>>>(es0, bucketCnt, es, counts,
                                      ovfCnt, ovfRow, ovfCol, ovfVal);
    spmm_ell<<<N_NODES / 32, 256, 0, stream>>>(y, es, counts, bias, out);
    ovf_fix<<<16, 256, 0, stream>>>(y, ovfRow, ovfCol, ovfVal, ovfCnt, out);
}